// Round 3
// baseline (270.803 us; speedup 1.0000x reference)
//
#include <hip/hip_runtime.h>
#include <math.h>

// Problem constants (B, L, D) = (8, 4096, 1024)
#define BB 8
#define LL 4096
#define DD 1024
#define LM2 4094    // delta_increase terms per batch
#define CHUNK 32    // increases per BLOCK
#define NDELTA 33   // CHUNK+1 deltas per block
#define ROWS 34     // CHUNK+2 rows per block
#define NCH 128     // chunks per batch = ceil(LM2/CHUNK)
#define NBLK (BB * NCH)  // 1024 blocks -> exactly 4 blocks/CU, no tail

// One BLOCK (4 waves) handles CHUNK consecutive delta_increases for one batch.
// Wave w streams D-quarter w of each of the ROWS rows (1 float4/lane/row,
// fully coalesced 1 KB per load instruction). This is the round-1 compute
// structure, verified passing at 195.7 us. The ONLY change this round: the
// separate final_kernel dispatch is replaced by a decoupled last-block-done
// reduction (rocPRIM lookback pattern): each block release-publishes its
// partial, the last block acquire-reads all 1024 pairs with agent-scope
// atomic loads (correct across non-coherent per-XCD L2s) and reduces them
// in a FIXED order (deterministic, no float atomics).
__global__ __launch_bounds__(256, 4) void fused_kernel(const float* __restrict__ states,
                                                       const float* __restrict__ rmask,
                                                       const int* __restrict__ rpos,
                                                       float* __restrict__ pnum,
                                                       float* __restrict__ pden,
                                                       int* __restrict__ counter,
                                                       float* __restrict__ out) {
    const int tid = threadIdx.x;
    const int lane = tid & 63;
    const int wid = tid >> 6;
    const int b = blockIdx.x >> 7;        // / NCH
    const int c = blockIdx.x & (NCH - 1); // % NCH
    const int t0 = c * CHUNK;             // first increase index of this block

    // Wave wid owns float4 columns [wid*64 .. wid*64+63]; lane -> one float4.
    const float4* base = (const float4*)states + (size_t)b * (LL * (DD / 4)) + wid * 64 + lane;

    float partial[NDELTA];

    float4 p = base[(size_t)t0 * (DD / 4)];
    #pragma unroll
    for (int r = 1; r < ROWS; ++r) {
        int row = t0 + r;
        if (row > LL - 1) row = LL - 1;  // clamp (dup row -> delta 0, masked out)
        float4 cur = base[(size_t)row * (DD / 4)];
        float s = 0.0f, d;
        d = cur.x - p.x; s += d * d;
        d = cur.y - p.y; s += d * d;
        d = cur.z - p.z; s += d * d;
        d = cur.w - p.w; s += d * d;
        partial[r - 1] = s;
        p = cur;
    }

    // Butterfly-reduce each partial across the 64 lanes; lane d keeps the
    // quarter-sum for delta t0+d.
    float qs = 0.0f;
    #pragma unroll
    for (int d2 = 0; d2 < NDELTA; ++d2) {
        float s = partial[d2];
        #pragma unroll
        for (int off = 1; off < 64; off <<= 1) s += __shfl_xor(s, off);
        if (lane == d2) qs = s;
    }

    // Combine the 4 D-quarters in LDS, then wave 0 finishes the chunk.
    __shared__ float qsum[4][NDELTA];
    __shared__ int isLast;
    if (lane < NDELTA) qsum[wid][lane] = qs;
    __syncthreads();

    if (wid == 0) {
        float dval = 0.0f;
        if (lane < NDELTA)
            dval = sqrtf(qsum[0][lane] + qsum[1][lane] + qsum[2][lane] + qsum[3][lane]);
        float dnext = __shfl_down(dval, 1);  // lane j gets delta[t0+j+1]

        const int t = t0 + lane;
        const bool valid = (lane < CHUNK) && (t < LM2);
        float inc = dnext - dval;
        inc = inc > 0.0f ? inc : 0.0f;
        int midx = b * LL + t + 2;
        if (midx > BB * LL - 1) midx = BB * LL - 1;  // safe even if speculated
        float m = valid ? rmask[midx] : 0.0f;
        const int rp = rpos[b];
        int dist = rp - t - 2;
        if (dist < 0) dist = 0;
        const float wgt = (dist < 5) ? (2.0f + (float)(5 - dist) * 0.5f) : 1.0f;
        float num = valid ? inc * m * wgt : 0.0f;
        float den = m;  // already 0 when invalid

        #pragma unroll
        for (int off = 32; off > 0; off >>= 1) {
            num += __shfl_down(num, off);
            den += __shfl_down(den, off);
        }
        if (lane == 0) {
            pnum[blockIdx.x] = num;
            pden[blockIdx.x] = den;
            // Release: make the partials visible at agent (device) scope,
            // then bump the done-counter.
            __threadfence();
            int old = __hip_atomic_fetch_add(counter, 1, __ATOMIC_ACQ_REL,
                                             __HIP_MEMORY_SCOPE_AGENT);
            isLast = (old == NBLK - 1);
        }
    }
    __syncthreads();

    if (isLast) {
        // This block saw all NBLK release-adds -> acquire side. Agent-scope
        // atomic loads bypass the (non-coherent) per-XCD L2 caches.
        float n = 0.0f, d = 0.0f;
        #pragma unroll
        for (int k = 0; k < NBLK / 256; ++k) {
            n += __hip_atomic_load(&pnum[tid + 256 * k], __ATOMIC_RELAXED,
                                   __HIP_MEMORY_SCOPE_AGENT);
            d += __hip_atomic_load(&pden[tid + 256 * k], __ATOMIC_RELAXED,
                                   __HIP_MEMORY_SCOPE_AGENT);
        }
        #pragma unroll
        for (int off = 32; off > 0; off >>= 1) {
            n += __shfl_down(n, off);
            d += __shfl_down(d, off);
        }
        __shared__ float bn[4], bd[4];
        if (lane == 0) { bn[wid] = n; bd[wid] = d; }
        __syncthreads();
        if (tid == 0) {
            float N = bn[0] + bn[1] + bn[2] + bn[3];
            float D = bd[0] + bd[1] + bd[2] + bd[3];
            out[0] = N / (D + 1e-9f);
        }
    }
}

extern "C" void kernel_launch(void* const* d_in, const int* in_sizes, int n_in,
                              void* d_out, int out_size, void* d_ws, size_t ws_size,
                              hipStream_t stream) {
    const float* states = (const float*)d_in[0];
    const float* rmask  = (const float*)d_in[1];
    const int*   rpos   = (const int*)d_in[2];
    float* out = (float*)d_out;

    float* ws   = (float*)d_ws;
    float* pnum = ws;              // NBLK floats
    float* pden = ws + NBLK;       // NBLK floats
    int*   counter = (int*)(ws + 2 * NBLK);

    // Workspace is poisoned between iterations -> zero the done-counter.
    // 4-byte async memset is graph-capturable and costs ~1-2 us of dispatch.
    hipMemsetAsync(counter, 0, sizeof(int), stream);

    fused_kernel<<<NBLK, 256, 0, stream>>>(states, rmask, rpos, pnum, pden, counter, out);
}

// Round 4
// 195.023 us; speedup vs baseline: 1.3886x; 1.3886x over previous
//
#include <hip/hip_runtime.h>
#include <math.h>

// Problem constants (B, L, D) = (8, 4096, 1024)
#define BB 8
#define LL 4096
#define DD 1024
#define LM2 4094    // delta_increase terms per batch
#define CHUNK 32    // increases per BLOCK
#define NDELTA 33   // CHUNK+1 deltas per block
#define ROWS 34     // CHUNK+2 rows per block
#define NCH 128     // chunks per batch = ceil(LM2/CHUNK)
#define NBLK (BB * NCH)  // 1024 blocks -> exactly 4 blocks/CU, no tail

// One BLOCK (4 waves) handles CHUNK consecutive delta_increases for one batch.
// Wave w streams D-quarter w of each of the ROWS rows (1 float4/lane/row,
// fully coalesced 1 KB per load instruction).
//
// Round-3 post-mortem (rocprof): partial[33] live across the loop forced a
// scratch spill at VGPR=40 -> 130 us latency-stalled kernel. Fix: butterfly-
// reduce each row's quarter-sum IMMEDIATELY inside the loop (lane r-1 keeps
// it). Live set is ~10 VGPRs -> no spill possible, and the compiler has
// ~100 spare VGPRs under the (256,4) cap for deep load pipelining. The
// 33x6 shfl_xor ops ride the otherwise-idle LDS pipe, hidden under the
// HBM stream. Downstream epilogue is byte-identical to the verified
// round-1 kernel. The round-3 single-dispatch fence/atomic scheme is
// reverted (per-block L2 writeback/invalidate cost +75 us).
__global__ __launch_bounds__(256, 4) void fused_kernel(const float* __restrict__ states,
                                                       const float* __restrict__ rmask,
                                                       const int* __restrict__ rpos,
                                                       float* __restrict__ pnum,
                                                       float* __restrict__ pden) {
    const int tid = threadIdx.x;
    const int lane = tid & 63;
    const int wid = tid >> 6;
    const int b = blockIdx.x >> 7;        // / NCH
    const int c = blockIdx.x & (NCH - 1); // % NCH
    const int t0 = c * CHUNK;             // first increase index of this block

    // Wave wid owns float4 columns [wid*64 .. wid*64+63]; lane -> one float4.
    const float4* base = (const float4*)states + (size_t)b * (LL * (DD / 4)) + wid * 64 + lane;

    float qs = 0.0f;  // lane d (< NDELTA) ends up holding quarter-sum of delta t0+d
    float4 p = base[(size_t)t0 * (DD / 4)];
    #pragma unroll
    for (int r = 1; r < ROWS; ++r) {
        int row = t0 + r;
        if (row > LL - 1) row = LL - 1;  // clamp (dup row -> delta 0, masked out)
        float4 cur = base[(size_t)row * (DD / 4)];
        float s, d;
        d = cur.x - p.x; s = d * d;
        d = cur.y - p.y; s = fmaf(d, d, s);
        d = cur.z - p.z; s = fmaf(d, d, s);
        d = cur.w - p.w; s = fmaf(d, d, s);
        // Reduce this row's quarter-sum across the wave NOW (no live array).
        #pragma unroll
        for (int off = 1; off < 64; off <<= 1) s += __shfl_xor(s, off);
        if (lane == r - 1) qs = s;
        p = cur;
    }

    // Combine the 4 D-quarters in LDS, then wave 0 finishes the chunk.
    __shared__ float qsum[4][NDELTA];
    if (lane < NDELTA) qsum[wid][lane] = qs;
    __syncthreads();

    if (wid == 0) {
        float dval = 0.0f;
        if (lane < NDELTA)
            dval = sqrtf(qsum[0][lane] + qsum[1][lane] + qsum[2][lane] + qsum[3][lane]);
        float dnext = __shfl_down(dval, 1);  // lane j gets delta[t0+j+1]

        const int t = t0 + lane;
        const bool valid = (lane < CHUNK) && (t < LM2);
        float inc = dnext - dval;
        inc = inc > 0.0f ? inc : 0.0f;
        int midx = b * LL + t + 2;
        if (midx > BB * LL - 1) midx = BB * LL - 1;  // safe even if speculated
        float m = valid ? rmask[midx] : 0.0f;
        const int rp = rpos[b];
        int dist = rp - t - 2;
        if (dist < 0) dist = 0;
        const float wgt = (dist < 5) ? (2.0f + (float)(5 - dist) * 0.5f) : 1.0f;
        float num = valid ? inc * m * wgt : 0.0f;
        float den = m;  // already 0 when invalid

        #pragma unroll
        for (int off = 32; off > 0; off >>= 1) {
            num += __shfl_down(num, off);
            den += __shfl_down(den, off);
        }
        if (lane == 0) {
            pnum[blockIdx.x] = num;
            pden[blockIdx.x] = den;
        }
    }
}

// Reduce the NBLK=1024 partials in one block and divide.
__global__ __launch_bounds__(1024) void final_kernel(const float* __restrict__ pnum,
                                                     const float* __restrict__ pden,
                                                     float* __restrict__ out) {
    const int tid = threadIdx.x;
    const int lane = tid & 63;
    const int wid = tid >> 6;  // 16 waves
    float n = pnum[tid];
    float d = pden[tid];
    #pragma unroll
    for (int off = 32; off > 0; off >>= 1) {
        n += __shfl_down(n, off);
        d += __shfl_down(d, off);
    }
    __shared__ float ln[16], ld[16];
    if (lane == 0) { ln[wid] = n; ld[wid] = d; }
    __syncthreads();
    if (tid == 0) {
        float N = 0.0f, D = 0.0f;
        #pragma unroll
        for (int i = 0; i < 16; ++i) { N += ln[i]; D += ld[i]; }
        out[0] = N / (D + 1e-9f);
    }
}

extern "C" void kernel_launch(void* const* d_in, const int* in_sizes, int n_in,
                              void* d_out, int out_size, void* d_ws, size_t ws_size,
                              hipStream_t stream) {
    const float* states = (const float*)d_in[0];
    const float* rmask  = (const float*)d_in[1];
    const int*   rpos   = (const int*)d_in[2];
    float* out = (float*)d_out;

    float* ws   = (float*)d_ws;
    float* pnum = ws;          // NBLK floats
    float* pden = ws + NBLK;   // NBLK floats

    fused_kernel<<<NBLK, 256, 0, stream>>>(states, rmask, rpos, pnum, pden);
    final_kernel<<<1, 1024, 0, stream>>>(pnum, pden, out);
}